// Round 3
// baseline (253.243 us; speedup 1.0000x reference)
//
#include <hip/hip_runtime.h>

typedef __bf16 bf16x8 __attribute__((ext_vector_type(8)));
typedef __bf16 bf16x4 __attribute__((ext_vector_type(4)));
typedef float f32x4 __attribute__((ext_vector_type(4)));
typedef float f32x16 __attribute__((ext_vector_type(16)));

__device__ __forceinline__ f32x4 mfma16(bf16x8 a, bf16x8 b, f32x4 c) {
  return __builtin_amdgcn_mfma_f32_16x16x32_bf16(a, b, c, 0, 0, 0);
}
__device__ __forceinline__ f32x16 mfma32(bf16x8 a, bf16x8 b, f32x16 c) {
  return __builtin_amdgcn_mfma_f32_32x32x16_bf16(a, b, c, 0, 0, 0);
}

// ---------------------------------------------------------------------------
// K0: convert Wf(32x256) | Wg(32x256) | Wh(256x256) fp32 -> Wb bf16 [320][256]
// ---------------------------------------------------------------------------
__global__ void wcvt_kernel(const float* __restrict__ Wf, const float* __restrict__ Wg,
                            const float* __restrict__ Wh, __bf16* __restrict__ Wb) {
  int i = blockIdx.x * 256 + threadIdx.x;  // 0..81919
  float v;
  if (i < 8192)       v = Wf[i];
  else if (i < 16384) v = Wg[i - 8192];
  else                v = Wh[i - 16384];
  Wb[i] = (__bf16)v;
}

// ---------------------------------------------------------------------------
// K1: projections. Grid 512 = b(4) x ntile(128 of 32 rows). 512 thr = 8 waves
// (wave: nh = wg&1 -> 16 n-rows, oh = wg>>1 -> 5 o-tiles of 16, o=oh*80+...).
//   O^T[n][o] = sum_c x[c][n] * Wb[o][c] + bias[o],  o in 0..319
//   o<64  -> fgT[b][n][o]   bf16 (Q|K fragment layout)
//   o>=64 -> hb[b][o-64][n] bf16 (j-contiguous, via LDS transpose)
// ---------------------------------------------------------------------------
__global__ __launch_bounds__(512) void proj_kernel(
    const float* __restrict__ x, const float* __restrict__ bfv,
    const float* __restrict__ bgv, const float* __restrict__ bhv,
    const __bf16* __restrict__ Wb, __bf16* __restrict__ fgT,
    __bf16* __restrict__ hb) {
  __shared__ __align__(16) char smem[2560 + 18432];
  __bf16* xT = (__bf16*)smem;           // [32 n][40 c] bf16 (pad -> 2-way-free b128)
  __bf16* ho = (__bf16*)(smem + 2560);  // [256 c][36 n] bf16

  const int t = threadIdx.x;
  const int l = t & 63, wg = t >> 6, q = l >> 4, l15 = l & 15;
  const int nh = wg & 1, oh = wg >> 1;   // oh 0..3
  const int bi = blockIdx.x;
  const int b = bi >> 7;
  const int n0 = (bi & 127) << 5;

  const float* xb = x + (size_t)b * 256 * 4096;

  f32x4 acc[5];
#pragma unroll
  for (int i = 0; i < 5; i++) acc[i] = (f32x4){0.f, 0.f, 0.f, 0.f};

  const int c_rel = t >> 4;        // 0..31
  const int n2 = (t & 15) * 2;     // 0..30

#pragma unroll 1
  for (int kc = 0; kc < 8; kc++) {
    __syncthreads();  // protect xT from previous iteration's reads
    float2 v = *(const float2*)(xb + (size_t)(kc * 32 + c_rel) * 4096 + n0 + n2);
    xT[(n2 + 0) * 40 + c_rel] = (__bf16)v.x;
    xT[(n2 + 1) * 40 + c_rel] = (__bf16)v.y;
    __syncthreads();
    bf16x8 af = *(const bf16x8*)(xT + (nh * 16 + l15) * 40 + q * 8);
    const __bf16* wp = Wb + (size_t)(oh * 80 + l15) * 256 + kc * 32 + q * 8;
#pragma unroll
    for (int ot = 0; ot < 5; ot++) {
      bf16x8 bfr = *(const bf16x8*)(wp + (size_t)ot * 16 * 256);
      acc[ot] = mfma16(af, bfr, acc[ot]);
    }
  }

  // epilogue: bias + dual-layout store
#pragma unroll
  for (int ot = 0; ot < 5; ot++) {
    int o = oh * 80 + ot * 16 + l15;
    float bias = (o < 32) ? bfv[o] : (o < 64) ? bgv[o - 32] : bhv[o - 64];
#pragma unroll
    for (int r = 0; r < 4; r++) {
      int n_rel = nh * 16 + q * 4 + r;
      float val = acc[ot][r] + bias;
      if (o < 64) {
        fgT[((size_t)b * 4096 + n0 + n_rel) * 64 + o] = (__bf16)val;
      } else {
        ho[(o - 64) * 36 + n_rel] = (__bf16)val;
      }
    }
  }
  __syncthreads();
  // ho[c][n] -> hb[b][c][n0+n], coalesced u32 copies (16 lanes per c-row)
  unsigned short* hbu = (unsigned short*)hb + (size_t)b * 256 * 4096 + n0;
  const unsigned short* hou = (const unsigned short*)ho;
  for (int e = t; e < 4096; e += 512) {
    int c = e >> 4, nn = (e & 15) * 2;
    unsigned int vv = *(const unsigned int*)(hou + c * 36 + nn);
    *(unsigned int*)(hbu + (size_t)c * 4096 + nn) = vv;
  }
}

// ---------------------------------------------------------------------------
// K2: fused attention, split-j x4, producer-consumer wave specialization.
// Grid 1024 = 16 (b,jp) combos x 64 i-tiles, XCD-swizzled. 512 thr = 8 waves:
//   waves 0-3 (producers): one 32x32 S tile each (i2=w>>1, j2=w&1):
//     S = Q*K^T (32x32x16 MFMA, K read ONCE per block), raw exp (no max:
//     |s|<~40 << 88), rowsum accum in regs, P -> LDS (dbuf, XOR-swizzled).
//   waves 4-7 (consumers): O^T[c][i] += V^T * P^T. A-frag = V^T rows straight
//     from L2 (hb is j-contiguous = A layout; V never touches LDS). B-frag =
//     P from LDS (uniform-8 bank pattern = conflict-free-equivalent b128).
// One barrier per iter. 2 blocks/CU (VGPR-capped 128), acc 4x16 fp32.
// ---------------------------------------------------------------------------
__global__ __launch_bounds__(512, 4) void attn_kernel(
    const __bf16* __restrict__ fgT, const __bf16* __restrict__ hb,
    __bf16* __restrict__ pO, float* __restrict__ Lp) {
  __shared__ __align__(16) char smem[37120];
  // [0,8192) P buf0; [8192,16384) P buf1  (64 rows x 128B, 16B-chunk XOR swizzle)
  // [0,36864) epilogue stage bf16 [256][72]  (reuses P bufs after main loop)
  // [36864,37120) Lbuf fp32 [64]
  __bf16* pbuf0 = (__bf16*)smem;
  __bf16* pbuf1 = (__bf16*)(smem + 8192);
  __bf16* stage = (__bf16*)smem;
  float* Lbuf = (float*)(smem + 36864);

  const int t = threadIdx.x;
  const int l = t & 63, wid = t >> 6;
  const int h = l >> 5, l31 = l & 31;

  const int bi = blockIdx.x;
  const int xcd = bi & 7, slot = bi >> 3;
  const int combo = xcd * 2 + (slot & 1);          // (b,jp) pinned to one XCD
  const int b = combo >> 2, jp = combo & 3;
  const int n0 = (slot >> 1) << 6;                 // i-tile 0..63

  const __bf16* fgb = fgT + (size_t)b * 4096 * 64;
  const __bf16* hbb = hb + (size_t)b * 256 * 4096;
  const int jq0 = jp << 10;

  if (t < 64) Lbuf[t] = 0.f;

  // producer ids (valid wid<4); consumer id (valid wid>=4)
  const int i2 = wid >> 1, j2 = wid & 1;
  const int cw = wid - 4;

  float rs[16];
#pragma unroll
  for (int r = 0; r < 16; r++) rs[r] = 0.f;
  f32x16 acc[2][2] = {};

  auto produce = [&](int jg0, __bf16* buf) {
    const __bf16* qp = fgb + (size_t)(n0 + i2 * 32 + l31) * 64 + h * 8;
    bf16x8 qf0 = *(const bf16x8*)(qp);
    bf16x8 qf1 = *(const bf16x8*)(qp + 16);
    const __bf16* kp = fgb + (size_t)(jg0 + j2 * 32 + l31) * 64 + 32 + h * 8;
    bf16x8 kf0 = *(const bf16x8*)(kp);
    bf16x8 kf1 = *(const bf16x8*)(kp + 16);
    f32x16 s = {};
    s = mfma32(qf0, kf0, s);
    s = mfma32(qf1, kf1, s);
#pragma unroll
    for (int r = 0; r < 16; r++) {
      float p = __expf(s[r]);
      rs[r] += p;
      int il = i2 * 32 + (r & 3) + 8 * (r >> 2) + 4 * h;   // C/D row (m74/m101)
      int jl = j2 * 32 + l31;                              // C/D col
      buf[il * 64 + ((((jl >> 3) ^ (il & 7)) << 3) | (jl & 7))] = (__bf16)p;
    }
  };

  auto consume = [&](int it, const __bf16* buf) {
    const int j0 = jq0 + (it << 6);
    bf16x8 vf[2][4];
#pragma unroll
    for (int c2 = 0; c2 < 2; c2++) {
      const __bf16* vp = hbb + (size_t)(cw * 64 + c2 * 32 + l31) * 4096 + j0 + h * 8;
#pragma unroll
      for (int k = 0; k < 4; k++)
        vf[c2][k] = *(const bf16x8*)(vp + k * 16);
    }
    const int px = l31 & 7;
#pragma unroll
    for (int k = 0; k < 4; k++) {
      int cp = ((k * 2 + h) ^ px) << 3;
      bf16x8 pf0 = *(const bf16x8*)(buf + l31 * 64 + cp);          // i2=0 rows
      bf16x8 pf1 = *(const bf16x8*)(buf + (32 + l31) * 64 + cp);   // i2=1 rows
      acc[0][0] = mfma32(vf[0][k], pf0, acc[0][0]);
      acc[0][1] = mfma32(vf[0][k], pf1, acc[0][1]);
      acc[1][0] = mfma32(vf[1][k], pf0, acc[1][0]);
      acc[1][1] = mfma32(vf[1][k], pf1, acc[1][1]);
    }
  };

  // software pipeline: P(0) produced pre-loop; in iter it, consumers eat
  // buf[it&1] while producers fill buf[(it+1)&1]. One barrier per iter.
  if (wid < 4) produce(jq0, pbuf0);
  __syncthreads();
#pragma unroll 1
  for (int it = 0; it < 16; ++it) {
    if (wid >= 4) {
      consume(it, (it & 1) ? pbuf1 : pbuf0);
    } else if (it < 15) {
      produce(jq0 + ((it + 1) << 6), ((it + 1) & 1) ? pbuf1 : pbuf0);
    }
    __syncthreads();
  }

  // epilogue: consumers stage O^T (c-rows) as bf16; producers finalize rowsums
  if (wid >= 4) {
#pragma unroll
    for (int c2 = 0; c2 < 2; c2++)
#pragma unroll
      for (int ii = 0; ii < 2; ii++)
#pragma unroll
        for (int r = 0; r < 16; r++) {
          int cl = cw * 64 + c2 * 32 + (r & 3) + 8 * (r >> 2) + 4 * h;
          int il = ii * 32 + l31;
          stage[cl * 72 + il] = (__bf16)acc[c2][ii][r];
        }
  } else {
#pragma unroll
    for (int r = 0; r < 16; r++) {
      float s = rs[r];
      s += __shfl_xor(s, 1); s += __shfl_xor(s, 2); s += __shfl_xor(s, 4);
      s += __shfl_xor(s, 8); s += __shfl_xor(s, 16);
      if (l31 == 0)
        atomicAdd(&Lbuf[i2 * 32 + (r & 3) + 8 * (r >> 2) + 4 * h], s);
    }
  }
  __syncthreads();

  // stage[256][72] -> pO (coalesced u32), Lbuf -> Lp
  unsigned short* ob = (unsigned short*)pO + (size_t)(jp * 4 + b) * 256 * 4096 + n0;
  const unsigned short* su = (const unsigned short*)stage;
#pragma unroll 1
  for (int e = t; e < 8192; e += 512) {
    int c = e >> 5, pr = (e & 31) * 2;
    unsigned int v = *(const unsigned int*)(su + c * 72 + pr);
    *(unsigned int*)(ob + (size_t)c * 4096 + pr) = v;
  }
  if (t < 64) Lp[(size_t)(jp * 4 + b) * 4096 + n0 + t] = Lbuf[t];
}

// ---------------------------------------------------------------------------
// K3: combine partials + normalize + residual.
//   out[b][c][i] = gamma * (sum_jp pO[jp][b][c][i]) / (sum_jp Lp[jp][b][i]) + x
// ---------------------------------------------------------------------------
__global__ __launch_bounds__(256) void norm_kernel(
    const float* __restrict__ x, const float* __restrict__ gamma_p,
    const __bf16* __restrict__ pO, const float* __restrict__ Lp,
    float* __restrict__ out) {
  const int bc = blockIdx.x;           // b = bc>>8, c = bc&255
  const int b = bc >> 8;
  const float gm = gamma_p[0];
  const float* xr = x + (size_t)bc * 4096;
  float* orow = out + (size_t)bc * 4096;
  const __bf16* pbase = pO + (size_t)bc * 4096;   // +jp*4194304
  const float* lbase = Lp + (size_t)b * 4096;     // +jp*16384

  for (int i0 = threadIdx.x * 4; i0 < 4096; i0 += 1024) {
    float4 xv = *(const float4*)(xr + i0);
    float s0 = 0.f, s1 = 0.f, s2 = 0.f, s3 = 0.f;
    float l0 = 0.f, l1 = 0.f, l2 = 0.f, l3 = 0.f;
#pragma unroll
    for (int jp = 0; jp < 4; jp++) {
      bf16x4 pv = *(const bf16x4*)(pbase + (size_t)jp * 4194304 + i0);
      s0 += (float)pv[0]; s1 += (float)pv[1]; s2 += (float)pv[2]; s3 += (float)pv[3];
      float4 lv = *(const float4*)(lbase + (size_t)jp * 16384 + i0);
      l0 += lv.x; l1 += lv.y; l2 += lv.z; l3 += lv.w;
    }
    float4 ov;
    ov.x = gm * s0 / l0 + xv.x;
    ov.y = gm * s1 / l1 + xv.y;
    ov.z = gm * s2 / l2 + xv.z;
    ov.w = gm * s3 / l3 + xv.w;
    *(float4*)(orow + i0) = ov;
  }
}

// ---------------------------------------------------------------------------
extern "C" void kernel_launch(void* const* d_in, const int* in_sizes, int n_in,
                              void* d_out, int out_size, void* d_ws, size_t ws_size,
                              hipStream_t stream) {
  const float* x   = (const float*)d_in[0];
  const float* Wf  = (const float*)d_in[1];
  const float* bfv = (const float*)d_in[2];
  const float* Wg  = (const float*)d_in[3];
  const float* bgv = (const float*)d_in[4];
  const float* Wh  = (const float*)d_in[5];
  const float* bhv = (const float*)d_in[6];
  const float* gm  = (const float*)d_in[7];
  float* out = (float*)d_out;

  char* ws = (char*)d_ws;
  __bf16* Wb  = (__bf16*)ws;                      //   160 KiB  @ 0
  __bf16* fgT = (__bf16*)(ws + 262144);           //  2 MiB: [4][4096][64]
  __bf16* hb  = (__bf16*)(ws + 2359296);          //  8 MiB: [4][256][4096]
  __bf16* pO  = (__bf16*)(ws + 10747904);         // 32 MiB: [4jp][4][256][4096] bf16
  float*  Lp  = (float*)(ws + 44302336);          // 256 KiB: [4jp][4][4096] fp32

  hipLaunchKernelGGL(wcvt_kernel, dim3(320), dim3(256), 0, stream, Wf, Wg, Wh, Wb);
  hipLaunchKernelGGL(proj_kernel, dim3(512), dim3(512), 0, stream,
                     x, bfv, bgv, bhv, Wb, fgT, hb);
  hipLaunchKernelGGL(attn_kernel, dim3(1024), dim3(512), 0, stream,
                     fgT, hb, pO, Lp);
  hipLaunchKernelGGL(norm_kernel, dim3(1024), dim3(256), 0, stream,
                     x, gm, pO, Lp, out);
}

// Round 4
// 212.338 us; speedup vs baseline: 1.1926x; 1.1926x over previous
//
#include <hip/hip_runtime.h>

typedef __bf16 bf16x8 __attribute__((ext_vector_type(8)));
typedef __bf16 bf16x4 __attribute__((ext_vector_type(4)));
typedef float f32x4 __attribute__((ext_vector_type(4)));
typedef float f32x16 __attribute__((ext_vector_type(16)));

__device__ __forceinline__ f32x4 mfma16(bf16x8 a, bf16x8 b, f32x4 c) {
  return __builtin_amdgcn_mfma_f32_16x16x32_bf16(a, b, c, 0, 0, 0);
}
__device__ __forceinline__ f32x16 mfma32(bf16x8 a, bf16x8 b, f32x16 c) {
  return __builtin_amdgcn_mfma_f32_32x32x16_bf16(a, b, c, 0, 0, 0);
}

// ---------------------------------------------------------------------------
// K0: convert Wf(32x256) | Wg(32x256) | Wh(256x256) fp32 -> Wb bf16 [320][256]
// ---------------------------------------------------------------------------
__global__ void wcvt_kernel(const float* __restrict__ Wf, const float* __restrict__ Wg,
                            const float* __restrict__ Wh, __bf16* __restrict__ Wb) {
  int i = blockIdx.x * 256 + threadIdx.x;  // 0..81919
  float v;
  if (i < 8192)       v = Wf[i];
  else if (i < 16384) v = Wg[i - 8192];
  else                v = Wh[i - 16384];
  Wb[i] = (__bf16)v;
}

// ---------------------------------------------------------------------------
// K1: projections. Grid 512 = b(4) x ntile(128 of 32 rows). 512 thr = 8 waves
//   O^T[n][o] = sum_c x[c][n] * Wb[o][c] + bias[o],  o in 0..319
//   o<64  -> fgT[b][n][o]   bf16 (Q|K fragment layout)
//   o>=64 -> hb[b][o-64][n] bf16 (j-contiguous, via LDS transpose)
// ---------------------------------------------------------------------------
__global__ __launch_bounds__(512) void proj_kernel(
    const float* __restrict__ x, const float* __restrict__ bfv,
    const float* __restrict__ bgv, const float* __restrict__ bhv,
    const __bf16* __restrict__ Wb, __bf16* __restrict__ fgT,
    __bf16* __restrict__ hb) {
  __shared__ __align__(16) char smem[2560 + 18432];
  __bf16* xT = (__bf16*)smem;           // [32 n][40 c] bf16
  __bf16* ho = (__bf16*)(smem + 2560);  // [256 c][36 n] bf16

  const int t = threadIdx.x;
  const int l = t & 63, wg = t >> 6, q = l >> 4, l15 = l & 15;
  const int nh = wg & 1, oh = wg >> 1;   // oh 0..3
  const int bi = blockIdx.x;
  const int b = bi >> 7;
  const int n0 = (bi & 127) << 5;

  const float* xb = x + (size_t)b * 256 * 4096;

  f32x4 acc[5];
#pragma unroll
  for (int i = 0; i < 5; i++) acc[i] = (f32x4){0.f, 0.f, 0.f, 0.f};

  const int c_rel = t >> 4;        // 0..31
  const int n2 = (t & 15) * 2;     // 0..30

#pragma unroll 1
  for (int kc = 0; kc < 8; kc++) {
    __syncthreads();
    float2 v = *(const float2*)(xb + (size_t)(kc * 32 + c_rel) * 4096 + n0 + n2);
    xT[(n2 + 0) * 40 + c_rel] = (__bf16)v.x;
    xT[(n2 + 1) * 40 + c_rel] = (__bf16)v.y;
    __syncthreads();
    bf16x8 af = *(const bf16x8*)(xT + (nh * 16 + l15) * 40 + q * 8);
    const __bf16* wp = Wb + (size_t)(oh * 80 + l15) * 256 + kc * 32 + q * 8;
#pragma unroll
    for (int ot = 0; ot < 5; ot++) {
      bf16x8 bfr = *(const bf16x8*)(wp + (size_t)ot * 16 * 256);
      acc[ot] = mfma16(af, bfr, acc[ot]);
    }
  }

#pragma unroll
  for (int ot = 0; ot < 5; ot++) {
    int o = oh * 80 + ot * 16 + l15;
    float bias = (o < 32) ? bfv[o] : (o < 64) ? bgv[o - 32] : bhv[o - 64];
#pragma unroll
    for (int r = 0; r < 4; r++) {
      int n_rel = nh * 16 + q * 4 + r;
      float val = acc[ot][r] + bias;
      if (o < 64) {
        fgT[((size_t)b * 4096 + n0 + n_rel) * 64 + o] = (__bf16)val;
      } else {
        ho[(o - 64) * 36 + n_rel] = (__bf16)val;
      }
    }
  }
  __syncthreads();
  unsigned short* hbu = (unsigned short*)hb + (size_t)b * 256 * 4096 + n0;
  const unsigned short* hou = (const unsigned short*)ho;
  for (int e = t; e < 4096; e += 512) {
    int c = e >> 4, nn = (e & 15) * 2;
    unsigned int vv = *(const unsigned int*)(hou + c * 36 + nn);
    *(unsigned int*)(hbu + (size_t)c * 4096 + nn) = vv;
  }
}

// ---------------------------------------------------------------------------
// K2: fused attention, split-j x4, HOMOGENEOUS waves + register-tiled PV.
// Grid 512 = 16 (b,jp) x 32 i-tiles(128 rows), 2 blocks/CU. 512 thr = 8 waves.
// Per 64-j step:
//   produce: each wave one 32x32 S tile of S[128x64] (it_s=w>>1, jt=w&1):
//     2 QK MFMA32 (frags from L2, coalesced), raw exp (|s|<~40, no max),
//     rowsum in regs, P -> LDS dbuf [128i][64j] XOR-swizzled.
//   consume: wave (cp=w&3, ip=w>>2) owns O[64i x 64c]: 2x2 f32x16 acc (64 VGPR,
//     classic reuse), A=P from LDS, B=V from L2 (hb j-contiguous = B layout;
//     NO global_load_lds -> barrier needs no vmcnt drain). 16 MFMA32/wave/step.
// ONE barrier per step (dbuf). acc register-resident across all 16 steps.
// ---------------------------------------------------------------------------
__global__ __launch_bounds__(512, 4) void attn_kernel(
    const __bf16* __restrict__ fgT, const __bf16* __restrict__ hb,
    __bf16* __restrict__ pO, float* __restrict__ Lp) {
  __shared__ __align__(16) char smem[35328];
  // [0,32768): P dbuf 2 x [128i][64j] bf16 ; reused after loop as stage
  // stage: [128c][134i] bf16 = 34304 B (overlaps P dbuf)
  // [34304, 34816): Lbuf fp32 [128]
  __bf16* stage = (__bf16*)smem;
  float* Lbuf = (float*)(smem + 34304);

  const int t = threadIdx.x;
  const int l = t & 63, w = t >> 6;
  const int h = l >> 5, l31 = l & 31;

  const int bi = blockIdx.x;
  const int xcd = bi & 7, slot = bi >> 3;          // slot 0..63
  const int combo = xcd * 2 + (slot & 1);          // (b,jp) pinned to one XCD
  const int b = combo >> 2, jp = combo & 3;
  const int n0 = (slot >> 1) << 7;                 // i-tile base, 128 rows

  const __bf16* fgb = fgT + (size_t)b * 4096 * 64;
  const __bf16* hbb = hb + (size_t)b * 256 * 4096;
  const int jq0 = jp << 10;

  if (t < 128) Lbuf[t] = 0.f;

  // produce roles
  const int it_s = w >> 1, jt = w & 1;
  // consume roles
  const int cp = w & 3, ip = w >> 2;

  f32x16 acc[2][2] = {};   // [ci][ii]
  float rs[16];
#pragma unroll
  for (int r = 0; r < 16; r++) rs[r] = 0.f;

  const __bf16* qp = fgb + (size_t)(n0 + it_s * 32 + l31) * 64 + h * 8;
  const int swz_w = ((jt * 32 + l31) >> 3);        // write chunk idx (pre-xor)

  auto produce = [&](int step, __bf16* buf) {
    const int j0 = jq0 + (step << 6);
    bf16x8 qf0 = *(const bf16x8*)(qp);
    bf16x8 qf1 = *(const bf16x8*)(qp + 16);
    const __bf16* kp = fgb + (size_t)(j0 + jt * 32 + l31) * 64 + 32 + h * 8;
    bf16x8 kf0 = *(const bf16x8*)(kp);
    bf16x8 kf1 = *(const bf16x8*)(kp + 16);
    f32x16 s = {};
    s = mfma32(qf0, kf0, s);
    s = mfma32(qf1, kf1, s);
    const int j_loc = jt * 32 + l31;
#pragma unroll
    for (int r = 0; r < 16; r++) {
      float p = __expf(s[r]);
      rs[r] += p;
      int i_loc = it_s * 32 + (r & 3) + 8 * (r >> 2) + 4 * h;
      buf[i_loc * 64 + (((swz_w ^ (i_loc & 7)) << 3) | (j_loc & 7))] = (__bf16)p;
    }
  };

  auto consume = [&](int step, const __bf16* buf) {
    const int j0 = jq0 + (step << 6);
#pragma unroll
    for (int kc = 0; kc < 4; kc++) {
      bf16x8 vf[2], pf[2];
#pragma unroll
      for (int ci = 0; ci < 2; ci++)
        vf[ci] = *(const bf16x8*)(hbb + (size_t)(cp * 64 + ci * 32 + l31) * 4096 +
                                  j0 + kc * 16 + h * 8);
#pragma unroll
      for (int ii = 0; ii < 2; ii++)
        pf[ii] = *(const bf16x8*)(buf + (ip * 64 + ii * 32 + l31) * 64 +
                                  (((kc * 2 + h) ^ (l31 & 7)) << 3));
#pragma unroll
      for (int ci = 0; ci < 2; ci++)
#pragma unroll
        for (int ii = 0; ii < 2; ii++)
          acc[ci][ii] = mfma32(pf[ii], vf[ci], acc[ci][ii]);
    }
  };

  __bf16* pb0 = (__bf16*)smem;
  __bf16* pb1 = (__bf16*)(smem + 16384);

  produce(0, pb0);
  __syncthreads();
#pragma unroll 1
  for (int it = 0; it < 16; ++it) {
    consume(it, (it & 1) ? pb1 : pb0);
    if (it < 15) produce(it + 1, (it & 1) ? pb0 : pb1);
    __syncthreads();
  }

  // rowsums -> Lbuf (rows of wave's S i-tile; 2 waves (jt) share rows -> atomic)
#pragma unroll
  for (int r = 0; r < 16; r++) {
    float s = rs[r];
    s += __shfl_xor(s, 1, 32); s += __shfl_xor(s, 2, 32);
    s += __shfl_xor(s, 4, 32); s += __shfl_xor(s, 8, 32);
    s += __shfl_xor(s, 16, 32);
    if (l31 == 0) {
      int row = it_s * 32 + (r & 3) + 8 * (r >> 2) + 4 * h;
      atomicAdd(&Lbuf[row], s);
    }
  }

  // epilogue: two c-half passes through LDS stage [128c][134i] (pad -> no conflict)
  unsigned short* ob = (unsigned short*)pO + (size_t)(jp * 4 + b) * 256 * 4096 + n0;
#pragma unroll 1
  for (int p = 0; p < 2; p++) {
    __syncthreads();
    if ((cp >> 1) == p) {
#pragma unroll
      for (int ci = 0; ci < 2; ci++) {
        int c_loc = (cp & 1) * 64 + ci * 32 + l31;
#pragma unroll
        for (int ii = 0; ii < 2; ii++)
#pragma unroll
          for (int r = 0; r < 16; r++) {
            int i = ip * 64 + ii * 32 + (r & 3) + 8 * (r >> 2) + 4 * h;
            stage[c_loc * 134 + i] = (__bf16)acc[ci][ii][r];
          }
      }
    }
    __syncthreads();
    const unsigned short* su = (const unsigned short*)stage;
#pragma unroll 1
    for (int e = t; e < 8192; e += 512) {
      int c = e >> 6, i2 = (e & 63) * 2;
      unsigned int v = *(const unsigned int*)(su + c * 134 + i2);
      *(unsigned int*)(ob + (size_t)(p * 128 + c) * 4096 + i2) = v;
    }
  }
  __syncthreads();
  if (t < 128) Lp[(size_t)(jp * 4 + b) * 4096 + n0 + t] = Lbuf[t];
}

// ---------------------------------------------------------------------------
// K3: combine partials + normalize + residual.
//   out[b][c][i] = gamma * (sum_jp pO[jp][b][c][i]) / (sum_jp Lp[jp][b][i]) + x
// ---------------------------------------------------------------------------
__global__ __launch_bounds__(256) void norm_kernel(
    const float* __restrict__ x, const float* __restrict__ gamma_p,
    const __bf16* __restrict__ pO, const float* __restrict__ Lp,
    float* __restrict__ out) {
  const int bc = blockIdx.x;           // b = bc>>8, c = bc&255
  const int b = bc >> 8;
  const float gm = gamma_p[0];
  const float* xr = x + (size_t)bc * 4096;
  float* orow = out + (size_t)bc * 4096;
  const __bf16* pbase = pO + (size_t)bc * 4096;   // +jp*4194304
  const float* lbase = Lp + (size_t)b * 4096;     // +jp*16384

  for (int i0 = threadIdx.x * 4; i0 < 4096; i0 += 1024) {
    float4 xv = *(const float4*)(xr + i0);
    float s0 = 0.f, s1 = 0.f, s2 = 0.f, s3 = 0.f;
    float l0 = 0.f, l1 = 0.f, l2 = 0.f, l3 = 0.f;
#pragma unroll
    for (int jp = 0; jp < 4; jp++) {
      bf16x4 pv = *(const bf16x4*)(pbase + (size_t)jp * 4194304 + i0);
      s0 += (float)pv[0]; s1 += (float)pv[1]; s2 += (float)pv[2]; s3 += (float)pv[3];
      float4 lv = *(const float4*)(lbase + (size_t)jp * 16384 + i0);
      l0 += lv.x; l1 += lv.y; l2 += lv.z; l3 += lv.w;
    }
    float4 ov;
    ov.x = gm * s0 / l0 + xv.x;
    ov.y = gm * s1 / l1 + xv.y;
    ov.z = gm * s2 / l2 + xv.z;
    ov.w = gm * s3 / l3 + xv.w;
    *(float4*)(orow + i0) = ov;
  }
}

// ---------------------------------------------------------------------------
extern "C" void kernel_launch(void* const* d_in, const int* in_sizes, int n_in,
                              void* d_out, int out_size, void* d_ws, size_t ws_size,
                              hipStream_t stream) {
  const float* x   = (const float*)d_in[0];
  const float* Wf  = (const float*)d_in[1];
  const float* bfv = (const float*)d_in[2];
  const float* Wg  = (const float*)d_in[3];
  const float* bgv = (const float*)d_in[4];
  const float* Wh  = (const float*)d_in[5];
  const float* bhv = (const float*)d_in[6];
  const float* gm  = (const float*)d_in[7];
  float* out = (float*)d_out;

  char* ws = (char*)d_ws;
  __bf16* Wb  = (__bf16*)ws;                      //   160 KiB  @ 0
  __bf16* fgT = (__bf16*)(ws + 262144);           //  2 MiB: [4][4096][64]
  __bf16* hb  = (__bf16*)(ws + 2359296);          //  8 MiB: [4][256][4096]
  __bf16* pO  = (__bf16*)(ws + 10747904);         // 32 MiB: [4jp][4][256][4096] bf16
  float*  Lp  = (float*)(ws + 44302336);          // 256 KiB: [4jp][4][4096] fp32

  hipLaunchKernelGGL(wcvt_kernel, dim3(320), dim3(256), 0, stream, Wf, Wg, Wh, Wb);
  hipLaunchKernelGGL(proj_kernel, dim3(512), dim3(512), 0, stream,
                     x, bfv, bgv, bhv, Wb, fgT, hb);
  hipLaunchKernelGGL(attn_kernel, dim3(512), dim3(512), 0, stream,
                     fgT, hb, pO, Lp);
  hipLaunchKernelGGL(norm_kernel, dim3(1024), dim3(256), 0, stream,
                     x, gm, pO, Lp, out);
}

// Round 5
// 196.207 us; speedup vs baseline: 1.2907x; 1.0822x over previous
//
#include <hip/hip_runtime.h>

typedef __bf16 bf16x8 __attribute__((ext_vector_type(8)));
typedef __bf16 bf16x4 __attribute__((ext_vector_type(4)));
typedef float f32x4 __attribute__((ext_vector_type(4)));
typedef float f32x16 __attribute__((ext_vector_type(16)));

__device__ __forceinline__ f32x4 mfma16(bf16x8 a, bf16x8 b, f32x4 c) {
  return __builtin_amdgcn_mfma_f32_16x16x32_bf16(a, b, c, 0, 0, 0);
}
__device__ __forceinline__ f32x16 mfma32(bf16x8 a, bf16x8 b, f32x16 c) {
  return __builtin_amdgcn_mfma_f32_32x32x16_bf16(a, b, c, 0, 0, 0);
}

// ---------------------------------------------------------------------------
// K0: convert Wf(32x256) | Wg(32x256) | Wh(256x256) fp32 -> Wb bf16 [320][256]
// ---------------------------------------------------------------------------
__global__ void wcvt_kernel(const float* __restrict__ Wf, const float* __restrict__ Wg,
                            const float* __restrict__ Wh, __bf16* __restrict__ Wb) {
  int i = blockIdx.x * 256 + threadIdx.x;  // 0..81919
  float v;
  if (i < 8192)       v = Wf[i];
  else if (i < 16384) v = Wg[i - 8192];
  else                v = Wh[i - 16384];
  Wb[i] = (__bf16)v;
}

// ---------------------------------------------------------------------------
// K1: projections. Grid 512 = b(4) x ntile(128 of 32 rows). 512 thr = 8 waves
//   O^T[n][o] = sum_c x[c][n] * Wb[o][c] + bias[o],  o in 0..319
//   o<64  -> fgT[b][n][o]   bf16 (Q|K fragment layout)
//   o>=64 -> hb[b][o-64][n] bf16 (j-contiguous, via LDS transpose)
// ---------------------------------------------------------------------------
__global__ __launch_bounds__(512) void proj_kernel(
    const float* __restrict__ x, const float* __restrict__ bfv,
    const float* __restrict__ bgv, const float* __restrict__ bhv,
    const __bf16* __restrict__ Wb, __bf16* __restrict__ fgT,
    __bf16* __restrict__ hb) {
  __shared__ __align__(16) char smem[2560 + 18432];
  __bf16* xT = (__bf16*)smem;           // [32 n][40 c] bf16
  __bf16* ho = (__bf16*)(smem + 2560);  // [256 c][36 n] bf16

  const int t = threadIdx.x;
  const int l = t & 63, wg = t >> 6, q = l >> 4, l15 = l & 15;
  const int nh = wg & 1, oh = wg >> 1;   // oh 0..3
  const int bi = blockIdx.x;
  const int b = bi >> 7;
  const int n0 = (bi & 127) << 5;

  const float* xb = x + (size_t)b * 256 * 4096;

  f32x4 acc[5];
#pragma unroll
  for (int i = 0; i < 5; i++) acc[i] = (f32x4){0.f, 0.f, 0.f, 0.f};

  const int c_rel = t >> 4;        // 0..31
  const int n2 = (t & 15) * 2;     // 0..30

#pragma unroll 1
  for (int kc = 0; kc < 8; kc++) {
    __syncthreads();
    float2 v = *(const float2*)(xb + (size_t)(kc * 32 + c_rel) * 4096 + n0 + n2);
    xT[(n2 + 0) * 40 + c_rel] = (__bf16)v.x;
    xT[(n2 + 1) * 40 + c_rel] = (__bf16)v.y;
    __syncthreads();
    bf16x8 af = *(const bf16x8*)(xT + (nh * 16 + l15) * 40 + q * 8);
    const __bf16* wp = Wb + (size_t)(oh * 80 + l15) * 256 + kc * 32 + q * 8;
#pragma unroll
    for (int ot = 0; ot < 5; ot++) {
      bf16x8 bfr = *(const bf16x8*)(wp + (size_t)ot * 16 * 256);
      acc[ot] = mfma16(af, bfr, acc[ot]);
    }
  }

#pragma unroll
  for (int ot = 0; ot < 5; ot++) {
    int o = oh * 80 + ot * 16 + l15;
    float bias = (o < 32) ? bfv[o] : (o < 64) ? bgv[o - 32] : bhv[o - 64];
#pragma unroll
    for (int r = 0; r < 4; r++) {
      int n_rel = nh * 16 + q * 4 + r;
      float val = acc[ot][r] + bias;
      if (o < 64) {
        fgT[((size_t)b * 4096 + n0 + n_rel) * 64 + o] = (__bf16)val;
      } else {
        ho[(o - 64) * 36 + n_rel] = (__bf16)val;
      }
    }
  }
  __syncthreads();
  unsigned short* hbu = (unsigned short*)hb + (size_t)b * 256 * 4096 + n0;
  const unsigned short* hou = (const unsigned short*)ho;
  for (int e = t; e < 4096; e += 512) {
    int c = e >> 4, nn = (e & 15) * 2;
    unsigned int vv = *(const unsigned int*)(hou + c * 36 + nn);
    *(unsigned int*)(hbu + (size_t)c * 4096 + nn) = vv;
  }
}

// ---------------------------------------------------------------------------
// K2: fused attention, split-j x4, register-prefetch software pipeline.
// Grid 1024 = 16 (b,jp) combos x 64 i-tiles(64 rows), XCD-pinned. 256 thr =
// 4 waves, 3 blocks/CU (3 independent barrier domains). Per 64-j step:
//   - V(it+1) and K(it+1) are loaded into REGISTERS during step it (issued
//     before/inside consume, used after the next barrier) -> no global-load
//     latency on the barrier-to-barrier critical path (cp.async-style).
//   - produce: wave (it_s,jt) computes one 32x32 S tile (2 QK mfma32, raw
//     exp — |s|<~40 << 88 so no online max), rowsum in regs, P -> LDS dbuf
//     [64i][136j] (+8 pad: conflict-free scalar writes AND b128 reads).
//   - consume: wave w owns full 64i x 64c quadrant (c base w*64): A=P (LDS),
//     B=V (regs), 16 mfma32, acc 2x2 f32x16 (AGPRs).
// One barrier per step.
// ---------------------------------------------------------------------------
__global__ __launch_bounds__(256, 3) void attn_kernel(
    const __bf16* __restrict__ fgT, const __bf16* __restrict__ hb,
    __bf16* __restrict__ pO, float* __restrict__ Lp) {
  __shared__ __align__(16) char smem[35072];
  // [0,17408) P buf0 [64][136]; [17408,34816) P buf1
  // epilogue: stage bf16 [256][66] = 33792 overlays P bufs
  // [34816,35072): Lbuf fp32 [64]
  __bf16* pb0 = (__bf16*)smem;
  __bf16* pb1 = (__bf16*)(smem + 17408);
  __bf16* stage = (__bf16*)smem;
  float* Lbuf = (float*)(smem + 34816);

  const int t = threadIdx.x;
  const int l = t & 63, w = t >> 6;          // 4 waves
  const int h = l >> 5, l31 = l & 31;

  const int bi = blockIdx.x;
  const int xcd = bi & 7, slot = bi >> 3;    // slot 0..127
  const int combo = xcd * 2 + (slot & 1);    // (b,jp) pinned to one XCD
  const int b = combo >> 2, jp = combo & 3;
  const int n0 = (slot >> 1) << 6;           // i-tile base, 64 rows

  const __bf16* fgb = fgT + (size_t)b * 4096 * 64;
  const __bf16* hbb = hb + (size_t)b * 256 * 4096;
  const int jq0 = jp << 10;

  if (t < 64) Lbuf[t] = 0.f;

  const int it_s = w >> 1, jt = w & 1;       // producer tile ids

  // Q fragments, hoisted (loop-invariant)
  const __bf16* qp = fgb + (size_t)(n0 + it_s * 32 + l31) * 64 + h * 8;
  const bf16x8 qf0 = *(const bf16x8*)(qp);
  const bf16x8 qf1 = *(const bf16x8*)(qp + 16);

  f32x16 acc[2][2] = {};                     // [ci][ii] -> AGPRs
  float rs[16];
#pragma unroll
  for (int r = 0; r < 16; r++) rs[r] = 0.f;

  // V source: wave's c rows = w*64 + ci*32 + l31, j columns h*8 within chunk
  const __bf16* vbase = hbb + (size_t)(w * 64 + l31) * 4096 + h * 8;

  // ---- preloop: produce(0) into pb0, prefetch V(0) ----
  {
    const __bf16* kp = fgb + (size_t)(jq0 + jt * 32 + l31) * 64 + 32 + h * 8;
    bf16x8 kf0 = *(const bf16x8*)(kp);
    bf16x8 kf1 = *(const bf16x8*)(kp + 16);
    f32x16 s = {};
    s = mfma32(qf0, kf0, s);
    s = mfma32(qf1, kf1, s);
#pragma unroll
    for (int r = 0; r < 16; r++) {
      float p = __expf(s[r]);
      rs[r] += p;
      int i_loc = it_s * 32 + (r & 3) + 8 * (r >> 2) + 4 * h;
      pb0[i_loc * 136 + jt * 32 + l31] = (__bf16)p;
    }
  }
  bf16x8 vf[2][4];
#pragma unroll
  for (int ci = 0; ci < 2; ci++)
#pragma unroll
    for (int kc = 0; kc < 4; kc++)
      vf[ci][kc] = *(const bf16x8*)(vbase + (size_t)ci * 32 * 4096 + jq0 + kc * 16);
  __syncthreads();

  // ---- main loop: 16 steps of 64 j ----
#pragma unroll 1
  for (int it = 0; it < 16; ++it) {
    __bf16* buf = (it & 1) ? pb1 : pb0;
    __bf16* nb  = (it & 1) ? pb0 : pb1;
    const int jn = jq0 + (((it + 1) & 15) << 6);   // next step (wraps harmlessly)

    // K prefetch for produce(it+1) — issued first, consumed after consume
    bf16x8 kf0, kf1;
    if (it < 15) {
      const __bf16* kp = fgb + (size_t)(jn + jt * 32 + l31) * 64 + 32 + h * 8;
      kf0 = *(const bf16x8*)(kp);
      kf1 = *(const bf16x8*)(kp + 16);
    }

    // consume step it using prefetched vf; roll vf -> V(it+1) after each use
#pragma unroll
    for (int kc = 0; kc < 4; kc++) {
      bf16x8 pf0 = *(const bf16x8*)(buf + (size_t)(l31) * 136 + kc * 16 + h * 8);
      bf16x8 pf1 = *(const bf16x8*)(buf + (size_t)(32 + l31) * 136 + kc * 16 + h * 8);
      acc[0][0] = mfma32(pf0, vf[0][kc], acc[0][0]);
      acc[0][1] = mfma32(pf1, vf[0][kc], acc[0][1]);
      acc[1][0] = mfma32(pf0, vf[1][kc], acc[1][0]);
      acc[1][1] = mfma32(pf1, vf[1][kc], acc[1][1]);
      vf[0][kc] = *(const bf16x8*)(vbase + jn + kc * 16);
      vf[1][kc] = *(const bf16x8*)(vbase + (size_t)32 * 4096 + jn + kc * 16);
    }

    // produce step it+1 into the other buffer
    if (it < 15) {
      f32x16 s = {};
      s = mfma32(qf0, kf0, s);
      s = mfma32(qf1, kf1, s);
#pragma unroll
      for (int r = 0; r < 16; r++) {
        float p = __expf(s[r]);
        rs[r] += p;
        int i_loc = it_s * 32 + (r & 3) + 8 * (r >> 2) + 4 * h;
        nb[i_loc * 136 + jt * 32 + l31] = (__bf16)p;
      }
    }
    __syncthreads();
  }

  // rowsums (rows i = it_s*32 + pat; jt pair shares rows -> atomicAdd)
#pragma unroll
  for (int r = 0; r < 16; r++) {
    float s = rs[r];
    s += __shfl_xor(s, 1, 32); s += __shfl_xor(s, 2, 32);
    s += __shfl_xor(s, 4, 32); s += __shfl_xor(s, 8, 32);
    s += __shfl_xor(s, 16, 32);
    if (l31 == 0) {
      int row = it_s * 32 + (r & 3) + 8 * (r >> 2) + 4 * h;
      atomicAdd(&Lbuf[row], s);
    }
  }

  // epilogue: O^T tile -> LDS stage [256c][66i] (lane->c, reg-pattern->i)
#pragma unroll
  for (int ci = 0; ci < 2; ci++) {
    int c_loc = w * 64 + ci * 32 + l31;
#pragma unroll
    for (int ii = 0; ii < 2; ii++)
#pragma unroll
      for (int r = 0; r < 16; r++) {
        int i_loc = ii * 32 + (r & 3) + 8 * (r >> 2) + 4 * h;
        stage[(size_t)c_loc * 66 + i_loc] = (__bf16)acc[ci][ii][r];
      }
  }
  __syncthreads();

  // stage -> pO (coalesced u32), Lbuf -> Lp
  unsigned short* ob = (unsigned short*)pO + (size_t)(jp * 4 + b) * 256 * 4096 + n0;
  const unsigned short* su = (const unsigned short*)stage;
#pragma unroll 1
  for (int e = t; e < 8192; e += 256) {
    int c = e >> 5, i2 = (e & 31) * 2;
    unsigned int v = *(const unsigned int*)(su + c * 66 + i2);
    *(unsigned int*)(ob + (size_t)c * 4096 + i2) = v;
  }
  if (t < 64) Lp[(size_t)(jp * 4 + b) * 4096 + n0 + t] = Lbuf[t];
}

// ---------------------------------------------------------------------------
// K3: combine partials + normalize + residual.
//   out[b][c][i] = gamma * (sum_jp pO[jp][b][c][i]) / (sum_jp Lp[jp][b][i]) + x
// ---------------------------------------------------------------------------
__global__ __launch_bounds__(256) void norm_kernel(
    const float* __restrict__ x, const float* __restrict__ gamma_p,
    const __bf16* __restrict__ pO, const float* __restrict__ Lp,
    float* __restrict__ out) {
  const int bc = blockIdx.x;           // b = bc>>8, c = bc&255
  const int b = bc >> 8;
  const float gm = gamma_p[0];
  const float* xr = x + (size_t)bc * 4096;
  float* orow = out + (size_t)bc * 4096;
  const __bf16* pbase = pO + (size_t)bc * 4096;   // +jp*4194304
  const float* lbase = Lp + (size_t)b * 4096;     // +jp*16384

  for (int i0 = threadIdx.x * 4; i0 < 4096; i0 += 1024) {
    float4 xv = *(const float4*)(xr + i0);
    float s0 = 0.f, s1 = 0.f, s2 = 0.f, s3 = 0.f;
    float l0 = 0.f, l1 = 0.f, l2 = 0.f, l3 = 0.f;
#pragma unroll
    for (int jp = 0; jp < 4; jp++) {
      bf16x4 pv = *(const bf16x4*)(pbase + (size_t)jp * 4194304 + i0);
      s0 += (float)pv[0]; s1 += (float)pv[1]; s2 += (float)pv[2]; s3 += (float)pv[3];
      float4 lv = *(const float4*)(lbase + (size_t)jp * 16384 + i0);
      l0 += lv.x; l1 += lv.y; l2 += lv.z; l3 += lv.w;
    }
    float4 ov;
    ov.x = gm * s0 / l0 + xv.x;
    ov.y = gm * s1 / l1 + xv.y;
    ov.z = gm * s2 / l2 + xv.z;
    ov.w = gm * s3 / l3 + xv.w;
    *(float4*)(orow + i0) = ov;
  }
}

// ---------------------------------------------------------------------------
extern "C" void kernel_launch(void* const* d_in, const int* in_sizes, int n_in,
                              void* d_out, int out_size, void* d_ws, size_t ws_size,
                              hipStream_t stream) {
  const float* x   = (const float*)d_in[0];
  const float* Wf  = (const float*)d_in[1];
  const float* bfv = (const float*)d_in[2];
  const float* Wg  = (const float*)d_in[3];
  const float* bgv = (const float*)d_in[4];
  const float* Wh  = (const float*)d_in[5];
  const float* bhv = (const float*)d_in[6];
  const float* gm  = (const float*)d_in[7];
  float* out = (float*)d_out;

  char* ws = (char*)d_ws;
  __bf16* Wb  = (__bf16*)ws;                      //   160 KiB  @ 0
  __bf16* fgT = (__bf16*)(ws + 262144);           //  2 MiB: [4][4096][64]
  __bf16* hb  = (__bf16*)(ws + 2359296);          //  8 MiB: [4][256][4096]
  __bf16* pO  = (__bf16*)(ws + 10747904);         // 32 MiB: [4jp][4][256][4096] bf16
  float*  Lp  = (float*)(ws + 44302336);          // 256 KiB: [4jp][4][4096] fp32

  hipLaunchKernelGGL(wcvt_kernel, dim3(320), dim3(256), 0, stream, Wf, Wg, Wh, Wb);
  hipLaunchKernelGGL(proj_kernel, dim3(512), dim3(512), 0, stream,
                     x, bfv, bgv, bhv, Wb, fgT, hb);
  hipLaunchKernelGGL(attn_kernel, dim3(1024), dim3(256), 0, stream,
                     fgT, hb, pO, Lp);
  hipLaunchKernelGGL(norm_kernel, dim3(1024), dim3(256), 0, stream,
                     x, gm, pO, Lp, out);
}